// Round 21
// baseline (224.213 us; speedup 1.0000x reference)
//
#include <hip/hip_runtime.h>

#define NROWS 16384
#define KCODES 8192
#define DDIM 256
#define MARGIN 1.0f
#define SEG 192
#define NCT 16     // 512-col tiles (block sweeps all 8192 cols)
#define GATHER_BLOCKS (NROWS / 16)

typedef __attribute__((ext_vector_type(8))) short short8;
typedef __attribute__((ext_vector_type(4))) float f32x4;

// ---------------- helpers ----------------
__device__ inline unsigned short f2bf(float x) {
    unsigned u = __float_as_uint(x);
    return (unsigned short)((u + 0x7FFFu + ((u >> 16) & 1u)) >> 16);  // RNE
}

__device__ inline unsigned mbcnt64(unsigned long long m) {
    unsigned lo = __builtin_amdgcn_mbcnt_lo((unsigned)m, 0u);
    return __builtin_amdgcn_mbcnt_hi((unsigned)(m >> 32), lo);
}

__device__ inline void exact_rescore(const float* __restrict__ z, const float* __restrict__ cb,
                                     const float* __restrict__ z2g, const float* __restrict__ e2g,
                                     int grow, int gcol, unsigned long long* best) {
    const float4* av = reinterpret_cast<const float4*>(z + (size_t)grow * DDIM);
    const float4* bv = reinterpret_cast<const float4*>(cb + (size_t)gcol * DDIM);
    float dot = 0.f;
    #pragma unroll 8
    for (int j = 0; j < 64; ++j) {
        const float4 xa = av[j], xb = bv[j];
        dot = fmaf(xa.x, xb.x, fmaf(xa.y, xb.y, fmaf(xa.z, xb.z, fmaf(xa.w, xb.w, dot))));
    }
    const float de = z2g[grow] + e2g[gcol] - 2.0f * dot;
    const unsigned long long key =
        ((unsigned long long)__float_as_uint(de) << 32) | (unsigned)gcol;
    atomicMin(best + grow, key);
}

// ---------------- convert cb fp32 -> bf16 pre-tiled fragment layout + e2 + init ----------------
// chunk (g, kb2): 1 KB, slot s: row g*16 + (s&15), k = kb2*32 + (s>>4)*8 .. +8
__global__ __launch_bounds__(256) void k_convert(
    const float* __restrict__ cb, unsigned short* __restrict__ cb_t,
    float* __restrict__ e2,
    unsigned long long* best, float* accum, unsigned* counters, unsigned* gctr)
{
    const int tid = threadIdx.x;
    const int bx = blockIdx.x;
    if (bx < 64) {
        const int gid = bx * 256 + tid;
        best[gid] = 0xFFFFFFFFFFFFFFFFull;
    }
    if (bx == 0) {
        if (tid < 16) counters[tid * 16] = 0u;
        if (tid == 0) { accum[0] = 0.0f; gctr[0] = 0u; }
    }
    const int g = bx * 4 + (tid >> 6);       // 512 groups over 128 blocks
    const int lane = tid & 63;
    const int row = g * 16 + (lane & 15);
    const int ko = (lane >> 4) * 8;
    float ss = 0.f;
    #pragma unroll
    for (int kb2 = 0; kb2 < 8; ++kb2) {
        const float4* src = reinterpret_cast<const float4*>(cb + (size_t)row * DDIM + kb2 * 32 + ko);
        const float4 a = src[0], b = src[1];
        ss += a.x * a.x + a.y * a.y + a.z * a.z + a.w * a.w
            + b.x * b.x + b.y * b.y + b.z * b.z + b.w * b.w;
        short8 p;
        p[0] = (short)f2bf(a.x); p[1] = (short)f2bf(a.y); p[2] = (short)f2bf(a.z); p[3] = (short)f2bf(a.w);
        p[4] = (short)f2bf(b.x); p[5] = (short)f2bf(b.y); p[6] = (short)f2bf(b.z); p[7] = (short)f2bf(b.w);
        *reinterpret_cast<short8*>(cb_t + (((size_t)(g * 8 + kb2)) << 9) + lane * 8) = p;
    }
    ss += __shfl_xor(ss, 16);
    ss += __shfl_xor(ss, 32);
    if (lane < 16) e2[g * 16 + lane] = ss;
}

// ---------------- MFMA screen: A in LDS, B straight from L2/L3 to registers ----------------
// 64 rows x ALL 8192 cols per block; wave tile 32x64 (acc[2][4]).
// K-loop is BARRIER-FREE: per step each wave loads its 4 B fragments from cb_t
// (wave-uniform base + lane*16, 1KB coalesced, L2/L3-resident) + 2 A ds_reads + 8 MFMA,
// with s_setprio(1) around the MFMA cluster (waves free-run at different phases).
// Epilogue per tile: 2 lgkm-only barriers -> block-tight running threshold -> ballot emit.
// LDS: A 32K @0 | rowmin[8][64] @32768 | thrbuf[64] @34816 | wl 16xSEG @35072
__global__ __launch_bounds__(1024, 4) void k_screen(
    const float* __restrict__ z, const float* __restrict__ cbp,
    const unsigned short* __restrict__ cb_t,
    float* z2g, const float* __restrict__ e2g,
    unsigned long long* __restrict__ best,
    unsigned* __restrict__ counters, unsigned* __restrict__ list, unsigned C16)
{
    __shared__ __align__(16) char smem[47360];
    char* ldsA = smem;
    float* rowmin = (float*)(smem + 32768);    // [8][64]
    float* thrbuf = (float*)(smem + 34816);    // [64] running block min (incl. current tile)
    unsigned* wl_all = (unsigned*)(smem + 35072);

    const int tid = threadIdx.x;
    const int lane = tid & 63;
    const int wave = tid >> 6;     // 0..15
    const int wm = wave & 1;       // 32-row half
    const int wn = wave >> 1;      // 0..7 col-64 group
    const int lhi = lane >> 4;
    const int llo = lane & 15;

    const int rt = blockIdx.x;     // 256 blocks, 64-row bands
    const int row0 = rt * 64;

    // ---- prologue ----
    // fused z-convert: fp32 band -> bf16 fragments straight into ldsA (2 slots/thread)
    {
        const int c = tid >> 5;                // chunk 0..31: gl = c>>3, kb2 = c&7
        const int gl = c >> 3, kb2 = c & 7;
        const int sp = (tid & 31) * 2;
        #pragma unroll
        for (int i = 0; i < 2; ++i) {
            const int s = sp + i;
            const int row = gl * 16 + (s & 15);
            const int k = kb2 * 32 + (s >> 4) * 8;
            const float4* src = reinterpret_cast<const float4*>(z + (size_t)(row0 + row) * DDIM + k);
            const float4 a = src[0], b = src[1];
            short8 p;
            p[0] = (short)f2bf(a.x); p[1] = (short)f2bf(a.y); p[2] = (short)f2bf(a.z); p[3] = (short)f2bf(a.w);
            p[4] = (short)f2bf(b.x); p[5] = (short)f2bf(b.y); p[6] = (short)f2bf(b.z); p[7] = (short)f2bf(b.w);
            *reinterpret_cast<short8*>(ldsA + c * 1024 + s * 16) = p;
        }
    }

    // z2 for own band (additive per-row constant used by rescore keys)
    #pragma unroll
    for (int rr = 0; rr < 4; ++rr) {
        const int row = wave * 4 + rr;
        const float4 v = *reinterpret_cast<const float4*>(z + (size_t)(row0 + row) * DDIM + lane * 4);
        float s = v.x * v.x + v.y * v.y + v.z * v.z + v.w * v.w;
        #pragma unroll
        for (int off = 1; off < 64; off <<= 1) s += __shfl_xor(s, off);
        if (lane == 0) z2g[row0 + row] = s;
    }

    if (tid < 64) thrbuf[tid] = 3.0e38f;
    __syncthreads();   // ldsA writes + z2 complete

    unsigned* wl = wl_all + wave * SEG;

    #pragma unroll 1
    for (int ci = 0; ci < NCT; ++ci) {
        f32x4 acc[2][4];
        #pragma unroll
        for (int i = 0; i < 2; ++i)
            #pragma unroll
            for (int j = 0; j < 4; ++j) { acc[i][j][0]=0.f; acc[i][j][1]=0.f; acc[i][j][2]=0.f; acc[i][j][3]=0.f; }

        // ---- K loop: 8 steps of K=32, barrier-free, B from global (L2/L3) ----
        const char* bbase = (const char*)cb_t + (((size_t)((ci * 32 + wn * 4)) * 8) << 10) + lane * 16;
        #pragma unroll
        for (int kb2 = 0; kb2 < 8; ++kb2) {
            short8 bfr[4];
            #pragma unroll
            for (int fn = 0; fn < 4; ++fn)
                bfr[fn] = *reinterpret_cast<const short8*>(bbase + fn * 8192 + kb2 * 1024);
            __builtin_amdgcn_s_setprio(1);
            #pragma unroll
            for (int fm = 0; fm < 2; ++fm) {
                const short8 af = *reinterpret_cast<const short8*>(
                    ldsA + (((wm * 2 + fm) * 8) + kb2) * 1024 + lane * 16);
                #pragma unroll
                for (int fn = 0; fn < 4; ++fn)
                    acc[fm][fn] = __builtin_amdgcn_mfma_f32_16x16x32_bf16(af, bfr[fn], acc[fm][fn], 0, 0, 0);
            }
            __builtin_amdgcn_s_setprio(0);
        }

        // ---- epilogue: block-tight threshold (2 lgkm-only barriers) ----
        const int c0 = ci * 512 + wn * 64 + llo;
        float e2c[4];
        #pragma unroll
        for (int fn = 0; fn < 4; ++fn) e2c[fn] = e2g[c0 + fn * 16];

        // phase A: per-wave per-row min over this tile's 64-col slice
        #pragma unroll
        for (int fm = 0; fm < 2; ++fm) {
            #pragma unroll
            for (int rg = 0; rg < 4; ++rg) {
                const int rl = wm * 32 + fm * 16 + lhi * 4 + rg;
                float d[4];
                #pragma unroll
                for (int fn = 0; fn < 4; ++fn) d[fn] = fmaf(-2.0f, acc[fm][fn][rg], e2c[fn]);
                float m = fminf(fminf(d[0], d[1]), fminf(d[2], d[3]));
                #pragma unroll
                for (int off = 1; off < 16; off <<= 1) m = fminf(m, __shfl_xor(m, off));
                if (llo == 0) rowmin[wn * 64 + rl] = m;
            }
        }
        asm volatile("s_waitcnt lgkmcnt(0)" ::: "memory");
        __builtin_amdgcn_s_barrier();
        __builtin_amdgcn_sched_barrier(0);

        // merge: running block min now INCLUDES the current tile
        if (tid < 64) {
            float a = rowmin[tid];
            #pragma unroll
            for (int q = 1; q < 8; ++q) a = fminf(a, rowmin[q * 64 + tid]);
            thrbuf[tid] = fminf(thrbuf[tid], a);
        }
        asm volatile("s_waitcnt lgkmcnt(0)" ::: "memory");
        __builtin_amdgcn_s_barrier();
        __builtin_amdgcn_sched_barrier(0);

        // phase B: emit vs tight threshold (recompute d from acc)
        unsigned wcount = 0;
        #pragma unroll
        for (int fm = 0; fm < 2; ++fm) {
            #pragma unroll
            for (int rg = 0; rg < 4; ++rg) {
                const int rl = wm * 32 + fm * 16 + lhi * 4 + rg;
                const float thr = thrbuf[rl] + MARGIN;
                float d[4];
                #pragma unroll
                for (int fn = 0; fn < 4; ++fn) d[fn] = fmaf(-2.0f, acc[fm][fn][rg], e2c[fn]);
                const bool hit = (d[0] <= thr) | (d[1] <= thr) | (d[2] <= thr) | (d[3] <= thr);
                if (__any(hit)) {
                    const int grow = row0 + rl;
                    #pragma unroll
                    for (int fn = 0; fn < 4; ++fn) {
                        const bool p = d[fn] <= thr;
                        const unsigned long long mask = __ballot(p);
                        if (mask) {
                            if (p) {
                                const unsigned pos = wcount + mbcnt64(mask);
                                const unsigned v = ((unsigned)grow << 13) | (unsigned)(c0 + fn * 16);
                                if (pos < SEG) wl[pos] = v;
                                else exact_rescore(z, cbp, z2g, e2g, grow, c0 + fn * 16, best);
                            }
                            wcount += (unsigned)__popcll(mask);
                        }
                    }
                }
            }
        }

        // per-tile flush: one atomic per wave to its shard
        const unsigned n = wcount < SEG ? wcount : SEG;
        unsigned base = 0;
        if (lane == 0 && n) base = atomicAdd(&counters[wave * 16], n);
        base = (unsigned)__shfl((int)base, 0);
        for (unsigned i = lane; i < n; i += 64) {
            const unsigned v = wl[i];
            const unsigned slot = base + i;
            if (slot < C16) list[(size_t)wave * C16 + slot] = v;
            else exact_rescore(z, cbp, z2g, e2g, (int)(v >> 13), (int)(v & 8191u), best);
        }
    }
}

// ---------------- exact rescore of sharded candidate lists (wave per candidate) ----------------
__global__ __launch_bounds__(256) void k_rescore(
    const float* __restrict__ z, const float* __restrict__ cbp,
    const float* __restrict__ z2g, const float* __restrict__ e2g,
    const unsigned* __restrict__ list, const unsigned* __restrict__ counters, unsigned C16,
    unsigned long long* best)
{
    const unsigned wid = (blockIdx.x * blockDim.x + threadIdx.x) >> 6;
    const unsigned nw = (gridDim.x * blockDim.x) >> 6;
    const int lane = threadIdx.x & 63;
    #pragma unroll 1
    for (int s = 0; s < 16; ++s) {
        const unsigned n = min(counters[s * 16], C16);
        const unsigned* shard = list + (size_t)s * C16;
        for (unsigned i = wid; i < n; i += nw) {
            const unsigned v = shard[i];
            const unsigned row = v >> 13, col = v & 8191u;
            const float4 a = *reinterpret_cast<const float4*>(z + (size_t)row * DDIM + lane * 4);
            const float4 b = *reinterpret_cast<const float4*>(cbp + (size_t)col * DDIM + lane * 4);
            float sdot = fmaf(a.x, b.x, fmaf(a.y, b.y, fmaf(a.z, b.z, a.w * b.w)));
            #pragma unroll
            for (int off = 1; off < 64; off <<= 1) sdot += __shfl_xor(sdot, off);
            if (lane == 0) {
                const float de = z2g[row] + e2g[col] - 2.0f * sdot;
                const unsigned long long key =
                    ((unsigned long long)__float_as_uint(de) << 32) | col;
                atomicMin(&best[row], key);
            }
        }
    }
}

// ---------------- gather + z_st + loss + final scalars (ticket) ----------------
__global__ __launch_bounds__(1024) void k_gather(
    const float* __restrict__ z, const float* __restrict__ cbp,
    const unsigned long long* __restrict__ best,
    float* __restrict__ out, float* __restrict__ accum, unsigned* __restrict__ gctr)
{
    __shared__ float wsum[16];
    const int tid = threadIdx.x;
    const int row = blockIdx.x * 16 + (tid >> 6);
    const int lane = tid & 63;
    const unsigned k = (unsigned)(best[row] & 0xFFFFFFFFull);
    const float4 ze = *reinterpret_cast<const float4*>(z + (size_t)row * DDIM + lane * 4);
    const float4 cq = *reinterpret_cast<const float4*>(cbp + (size_t)k * DDIM + lane * 4);
    float4 zst;
    zst.x = ze.x + (cq.x - ze.x); zst.y = ze.y + (cq.y - ze.y);
    zst.z = ze.z + (cq.z - ze.z); zst.w = ze.w + (cq.w - ze.w);
    *reinterpret_cast<float4*>(out + (size_t)row * DDIM + lane * 4) = zst;
    const float dx = cq.x - ze.x, dy = cq.y - ze.y, dz = cq.z - ze.z, dw = cq.w - ze.w;
    float s = dx * dx + dy * dy + dz * dz + dw * dw;
    #pragma unroll
    for (int off = 32; off > 0; off >>= 1) s += __shfl_down(s, off);
    if (lane == 0) {
        wsum[tid >> 6] = s;
        out[(size_t)NROWS * DDIM + row] = (float)k;
    }
    __syncthreads();
    if (tid == 0) {
        float tot = 0.f;
        #pragma unroll
        for (int i = 0; i < 16; ++i) tot += wsum[i];
        atomicAdd(accum, tot);
        __threadfence();
        const unsigned t = atomicAdd(gctr, 1u);
        if (t == GATHER_BLOCKS - 1) {
            const float total = atomicAdd(accum, 0.0f);
            const float m = total / (float)(NROWS * DDIM);
            out[(size_t)NROWS * DDIM + NROWS + 0] = m;
            out[(size_t)NROWS * DDIM + NROWS + 1] = m;
        }
    }
}

extern "C" void kernel_launch(void* const* d_in, const int* in_sizes, int n_in,
                              void* d_out, int out_size, void* d_ws, size_t ws_size,
                              hipStream_t stream)
{
    const float* z  = (const float*)d_in[0];
    const float* cb = (const float*)d_in[1];
    float* out = (float*)d_out;

    // bf16 pre-tiled codebook lives in d_out's z_st region (4 MB of 16.8 MB),
    // consumed by k_screen and fully overwritten afterwards by k_gather.
    unsigned short* cb_t = (unsigned short*)d_out;        // 4 MB

    char* ws = (char*)d_ws;
    unsigned long long* best = (unsigned long long*)ws;   // 131072 B
    float* e2      = (float*)(ws + 131072);               // 32768 B
    float* z2      = (float*)(ws + 163840);               // 65536 B
    float* accum   = (float*)(ws + 229376);
    unsigned* gctr = (unsigned*)(ws + 229380);
    unsigned* counters = (unsigned*)(ws + 229440);        // 16 shard counters, 64B apart
    unsigned* list = (unsigned*)(ws + 230464);
    unsigned C16 = 0;
    if (ws_size > 230464 + 64) {
        size_t c = (ws_size - 230464) / 4 / 16;
        if (c > (1u << 19)) c = (1u << 19);
        C16 = (unsigned)c;
    }

    k_convert<<<128, 256, 0, stream>>>(cb, cb_t, e2, best, accum, counters, gctr);
    k_screen<<<256, 1024, 0, stream>>>(z, cb, cb_t, z2, e2, best, counters, list, C16);
    k_rescore<<<512, 256, 0, stream>>>(z, cb, z2, e2, list, counters, C16, best);
    k_gather<<<GATHER_BLOCKS, 1024, 0, stream>>>(z, cb, best, out, accum, gctr);
}

// Round 22
// 210.359 us; speedup vs baseline: 1.0659x; 1.0659x over previous
//
#include <hip/hip_runtime.h>

#define NROWS 16384
#define KCODES 8192
#define DDIM 256
#define MARGIN 1.0f
#define SEG 192
#define NCT 16     // 512-col tiles (block sweeps all 8192 cols)
#define GATHER_BLOCKS (NROWS / 16)

typedef __attribute__((ext_vector_type(8))) short short8;
typedef __attribute__((ext_vector_type(4))) float f32x4;

// ---------------- helpers ----------------
__device__ inline unsigned short f2bf(float x) {
    unsigned u = __float_as_uint(x);
    return (unsigned short)((u + 0x7FFFu + ((u >> 16) & 1u)) >> 16);  // RNE
}

__device__ inline unsigned mbcnt64(unsigned long long m) {
    unsigned lo = __builtin_amdgcn_mbcnt_lo((unsigned)m, 0u);
    return __builtin_amdgcn_mbcnt_hi((unsigned)(m >> 32), lo);
}

__device__ inline void exact_rescore(const float* __restrict__ z, const float* __restrict__ cb,
                                     const float* __restrict__ z2g, const float* __restrict__ e2g,
                                     int grow, int gcol, unsigned long long* best) {
    const float4* av = reinterpret_cast<const float4*>(z + (size_t)grow * DDIM);
    const float4* bv = reinterpret_cast<const float4*>(cb + (size_t)gcol * DDIM);
    float dot = 0.f;
    #pragma unroll 8
    for (int j = 0; j < 64; ++j) {
        const float4 xa = av[j], xb = bv[j];
        dot = fmaf(xa.x, xb.x, fmaf(xa.y, xb.y, fmaf(xa.z, xb.z, fmaf(xa.w, xb.w, dot))));
    }
    const float de = z2g[grow] + e2g[gcol] - 2.0f * dot;
    const unsigned long long key =
        ((unsigned long long)__float_as_uint(de) << 32) | (unsigned)gcol;
    atomicMin(best + grow, key);
}

// ---------------- convert cb fp32 -> bf16 pre-tiled fragment layout + e2 + init ----------------
// chunk (g, kb2): 1 KB, slot s: row g*16 + (s&15), k = kb2*32 + (s>>4)*8 .. +8
__global__ __launch_bounds__(256) void k_convert(
    const float* __restrict__ cb, unsigned short* __restrict__ cb_t,
    float* __restrict__ e2,
    unsigned long long* best, float* accum, unsigned* counters, unsigned* gctr)
{
    const int tid = threadIdx.x;
    const int bx = blockIdx.x;
    if (bx < 64) {
        const int gid = bx * 256 + tid;
        best[gid] = 0xFFFFFFFFFFFFFFFFull;
    }
    if (bx == 0) {
        if (tid < 16) counters[tid * 16] = 0u;
        if (tid == 0) { accum[0] = 0.0f; gctr[0] = 0u; }
    }
    const int g = bx * 4 + (tid >> 6);       // 512 groups over 128 blocks
    const int lane = tid & 63;
    const int row = g * 16 + (lane & 15);
    const int ko = (lane >> 4) * 8;
    float ss = 0.f;
    #pragma unroll
    for (int kb2 = 0; kb2 < 8; ++kb2) {
        const float4* src = reinterpret_cast<const float4*>(cb + (size_t)row * DDIM + kb2 * 32 + ko);
        const float4 a = src[0], b = src[1];
        ss += a.x * a.x + a.y * a.y + a.z * a.z + a.w * a.w
            + b.x * b.x + b.y * b.y + b.z * b.z + b.w * b.w;
        short8 p;
        p[0] = (short)f2bf(a.x); p[1] = (short)f2bf(a.y); p[2] = (short)f2bf(a.z); p[3] = (short)f2bf(a.w);
        p[4] = (short)f2bf(b.x); p[5] = (short)f2bf(b.y); p[6] = (short)f2bf(b.z); p[7] = (short)f2bf(b.w);
        *reinterpret_cast<short8*>(cb_t + (((size_t)(g * 8 + kb2)) << 9) + lane * 8) = p;
    }
    ss += __shfl_xor(ss, 16);
    ss += __shfl_xor(ss, 32);
    if (lane < 16) e2[g * 16 + lane] = ss;
}

// ---------------- MFMA screen: A in LDS, B straight from L2/L3 to registers ----------------
// 64 rows x ALL 8192 cols per block; wave tile 32x64 (acc[2][4]).
// K-loop is BARRIER-FREE: per step each wave loads its 4 B fragments from cb_t
// (wave-uniform base + lane*16, 1KB coalesced, L2/L3-resident) + 2 A ds_reads + 8 MFMA.
// Epilogue per tile: 2 lgkm-only barriers -> block-tight running threshold -> ballot emit.
// LDS: A 32K @0 | rowmin[8][64] @32768 | thrbuf[64] @34816 | wl 16xSEG @35072
__global__ __launch_bounds__(1024, 4) void k_screen(
    const float* __restrict__ z, const float* __restrict__ cbp,
    const unsigned short* __restrict__ cb_t,
    float* z2g, const float* __restrict__ e2g,
    unsigned long long* __restrict__ best,
    unsigned* __restrict__ counters, unsigned* __restrict__ list, unsigned C16)
{
    __shared__ __align__(16) char smem[47360];
    char* ldsA = smem;
    float* rowmin = (float*)(smem + 32768);    // [8][64]
    float* thrbuf = (float*)(smem + 34816);    // [64] running block min (incl. current tile)
    unsigned* wl_all = (unsigned*)(smem + 35072);

    const int tid = threadIdx.x;
    const int lane = tid & 63;
    const int wave = tid >> 6;     // 0..15
    const int wm = wave & 1;       // 32-row half
    const int wn = wave >> 1;      // 0..7 col-64 group
    const int lhi = lane >> 4;
    const int llo = lane & 15;

    const int rt = blockIdx.x;     // 256 blocks, 64-row bands
    const int row0 = rt * 64;

    // ---- prologue ----
    // fused z-convert: fp32 band -> bf16 fragments straight into ldsA (2 slots/thread)
    {
        const int c = tid >> 5;                // chunk 0..31: gl = c>>3, kb2 = c&7
        const int gl = c >> 3, kb2 = c & 7;
        const int sp = (tid & 31) * 2;
        #pragma unroll
        for (int i = 0; i < 2; ++i) {
            const int s = sp + i;
            const int row = gl * 16 + (s & 15);
            const int k = kb2 * 32 + (s >> 4) * 8;
            const float4* src = reinterpret_cast<const float4*>(z + (size_t)(row0 + row) * DDIM + k);
            const float4 a = src[0], b = src[1];
            short8 p;
            p[0] = (short)f2bf(a.x); p[1] = (short)f2bf(a.y); p[2] = (short)f2bf(a.z); p[3] = (short)f2bf(a.w);
            p[4] = (short)f2bf(b.x); p[5] = (short)f2bf(b.y); p[6] = (short)f2bf(b.z); p[7] = (short)f2bf(b.w);
            *reinterpret_cast<short8*>(ldsA + c * 1024 + s * 16) = p;
        }
    }

    // z2 for own band (additive per-row constant used by rescore keys)
    #pragma unroll
    for (int rr = 0; rr < 4; ++rr) {
        const int row = wave * 4 + rr;
        const float4 v = *reinterpret_cast<const float4*>(z + (size_t)(row0 + row) * DDIM + lane * 4);
        float s = v.x * v.x + v.y * v.y + v.z * v.z + v.w * v.w;
        #pragma unroll
        for (int off = 1; off < 64; off <<= 1) s += __shfl_xor(s, off);
        if (lane == 0) z2g[row0 + row] = s;
    }

    if (tid < 64) thrbuf[tid] = 3.0e38f;
    __syncthreads();   // ldsA writes + z2 complete

    unsigned* wl = wl_all + wave * SEG;

    #pragma unroll 1
    for (int ci = 0; ci < NCT; ++ci) {
        f32x4 acc[2][4];
        #pragma unroll
        for (int i = 0; i < 2; ++i)
            #pragma unroll
            for (int j = 0; j < 4; ++j) { acc[i][j][0]=0.f; acc[i][j][1]=0.f; acc[i][j][2]=0.f; acc[i][j][3]=0.f; }

        // ---- K loop: 8 steps of K=32, barrier-free, B from global (L2/L3) ----
        const char* bbase = (const char*)cb_t + (((size_t)((ci * 32 + wn * 4)) * 8) << 10) + lane * 16;
        #pragma unroll
        for (int kb2 = 0; kb2 < 8; ++kb2) {
            short8 bfr[4];
            #pragma unroll
            for (int fn = 0; fn < 4; ++fn)
                bfr[fn] = *reinterpret_cast<const short8*>(bbase + fn * 8192 + kb2 * 1024);
            #pragma unroll
            for (int fm = 0; fm < 2; ++fm) {
                const short8 af = *reinterpret_cast<const short8*>(
                    ldsA + (((wm * 2 + fm) * 8) + kb2) * 1024 + lane * 16);
                #pragma unroll
                for (int fn = 0; fn < 4; ++fn)
                    acc[fm][fn] = __builtin_amdgcn_mfma_f32_16x16x32_bf16(af, bfr[fn], acc[fm][fn], 0, 0, 0);
            }
        }

        // ---- epilogue: block-tight threshold (2 lgkm-only barriers) ----
        const int c0 = ci * 512 + wn * 64 + llo;
        float e2c[4];
        #pragma unroll
        for (int fn = 0; fn < 4; ++fn) e2c[fn] = e2g[c0 + fn * 16];

        // phase A: per-wave per-row min over this tile's 64-col slice
        #pragma unroll
        for (int fm = 0; fm < 2; ++fm) {
            #pragma unroll
            for (int rg = 0; rg < 4; ++rg) {
                const int rl = wm * 32 + fm * 16 + lhi * 4 + rg;
                float d[4];
                #pragma unroll
                for (int fn = 0; fn < 4; ++fn) d[fn] = fmaf(-2.0f, acc[fm][fn][rg], e2c[fn]);
                float m = fminf(fminf(d[0], d[1]), fminf(d[2], d[3]));
                #pragma unroll
                for (int off = 1; off < 16; off <<= 1) m = fminf(m, __shfl_xor(m, off));
                if (llo == 0) rowmin[wn * 64 + rl] = m;
            }
        }
        asm volatile("s_waitcnt lgkmcnt(0)" ::: "memory");
        __builtin_amdgcn_s_barrier();
        __builtin_amdgcn_sched_barrier(0);

        // merge: running block min now INCLUDES the current tile
        if (tid < 64) {
            float a = rowmin[tid];
            #pragma unroll
            for (int q = 1; q < 8; ++q) a = fminf(a, rowmin[q * 64 + tid]);
            thrbuf[tid] = fminf(thrbuf[tid], a);
        }
        asm volatile("s_waitcnt lgkmcnt(0)" ::: "memory");
        __builtin_amdgcn_s_barrier();
        __builtin_amdgcn_sched_barrier(0);

        // phase B: emit vs tight threshold (recompute d from acc)
        unsigned wcount = 0;
        #pragma unroll
        for (int fm = 0; fm < 2; ++fm) {
            #pragma unroll
            for (int rg = 0; rg < 4; ++rg) {
                const int rl = wm * 32 + fm * 16 + lhi * 4 + rg;
                const float thr = thrbuf[rl] + MARGIN;
                float d[4];
                #pragma unroll
                for (int fn = 0; fn < 4; ++fn) d[fn] = fmaf(-2.0f, acc[fm][fn][rg], e2c[fn]);
                const bool hit = (d[0] <= thr) | (d[1] <= thr) | (d[2] <= thr) | (d[3] <= thr);
                if (__any(hit)) {
                    const int grow = row0 + rl;
                    #pragma unroll
                    for (int fn = 0; fn < 4; ++fn) {
                        const bool p = d[fn] <= thr;
                        const unsigned long long mask = __ballot(p);
                        if (mask) {
                            if (p) {
                                const unsigned pos = wcount + mbcnt64(mask);
                                const unsigned v = ((unsigned)grow << 13) | (unsigned)(c0 + fn * 16);
                                if (pos < SEG) wl[pos] = v;
                                else exact_rescore(z, cbp, z2g, e2g, grow, c0 + fn * 16, best);
                            }
                            wcount += (unsigned)__popcll(mask);
                        }
                    }
                }
            }
        }

        // per-tile flush: one atomic per wave to its shard
        const unsigned n = wcount < SEG ? wcount : SEG;
        unsigned base = 0;
        if (lane == 0 && n) base = atomicAdd(&counters[wave * 16], n);
        base = (unsigned)__shfl((int)base, 0);
        for (unsigned i = lane; i < n; i += 64) {
            const unsigned v = wl[i];
            const unsigned slot = base + i;
            if (slot < C16) list[(size_t)wave * C16 + slot] = v;
            else exact_rescore(z, cbp, z2g, e2g, (int)(v >> 13), (int)(v & 8191u), best);
        }
    }
}

// ---------------- exact rescore of sharded candidate lists (wave per candidate) ----------------
__global__ __launch_bounds__(256) void k_rescore(
    const float* __restrict__ z, const float* __restrict__ cbp,
    const float* __restrict__ z2g, const float* __restrict__ e2g,
    const unsigned* __restrict__ list, const unsigned* __restrict__ counters, unsigned C16,
    unsigned long long* best)
{
    const unsigned wid = (blockIdx.x * blockDim.x + threadIdx.x) >> 6;
    const unsigned nw = (gridDim.x * blockDim.x) >> 6;
    const int lane = threadIdx.x & 63;
    #pragma unroll 1
    for (int s = 0; s < 16; ++s) {
        const unsigned n = min(counters[s * 16], C16);
        const unsigned* shard = list + (size_t)s * C16;
        for (unsigned i = wid; i < n; i += nw) {
            const unsigned v = shard[i];
            const unsigned row = v >> 13, col = v & 8191u;
            const float4 a = *reinterpret_cast<const float4*>(z + (size_t)row * DDIM + lane * 4);
            const float4 b = *reinterpret_cast<const float4*>(cbp + (size_t)col * DDIM + lane * 4);
            float sdot = fmaf(a.x, b.x, fmaf(a.y, b.y, fmaf(a.z, b.z, a.w * b.w)));
            #pragma unroll
            for (int off = 1; off < 64; off <<= 1) sdot += __shfl_xor(sdot, off);
            if (lane == 0) {
                const float de = z2g[row] + e2g[col] - 2.0f * sdot;
                const unsigned long long key =
                    ((unsigned long long)__float_as_uint(de) << 32) | col;
                atomicMin(&best[row], key);
            }
        }
    }
}

// ---------------- gather + z_st + loss + final scalars (ticket) ----------------
__global__ __launch_bounds__(1024) void k_gather(
    const float* __restrict__ z, const float* __restrict__ cbp,
    const unsigned long long* __restrict__ best,
    float* __restrict__ out, float* __restrict__ accum, unsigned* __restrict__ gctr)
{
    __shared__ float wsum[16];
    const int tid = threadIdx.x;
    const int row = blockIdx.x * 16 + (tid >> 6);
    const int lane = tid & 63;
    const unsigned k = (unsigned)(best[row] & 0xFFFFFFFFull);
    const float4 ze = *reinterpret_cast<const float4*>(z + (size_t)row * DDIM + lane * 4);
    const float4 cq = *reinterpret_cast<const float4*>(cbp + (size_t)k * DDIM + lane * 4);
    float4 zst;
    zst.x = ze.x + (cq.x - ze.x); zst.y = ze.y + (cq.y - ze.y);
    zst.z = ze.z + (cq.z - ze.z); zst.w = ze.w + (cq.w - ze.w);
    *reinterpret_cast<float4*>(out + (size_t)row * DDIM + lane * 4) = zst;
    const float dx = cq.x - ze.x, dy = cq.y - ze.y, dz = cq.z - ze.z, dw = cq.w - ze.w;
    float s = dx * dx + dy * dy + dz * dz + dw * dw;
    #pragma unroll
    for (int off = 32; off > 0; off >>= 1) s += __shfl_down(s, off);
    if (lane == 0) {
        wsum[tid >> 6] = s;
        out[(size_t)NROWS * DDIM + row] = (float)k;
    }
    __syncthreads();
    if (tid == 0) {
        float tot = 0.f;
        #pragma unroll
        for (int i = 0; i < 16; ++i) tot += wsum[i];
        atomicAdd(accum, tot);
        __threadfence();
        const unsigned t = atomicAdd(gctr, 1u);
        if (t == GATHER_BLOCKS - 1) {
            const float total = atomicAdd(accum, 0.0f);
            const float m = total / (float)(NROWS * DDIM);
            out[(size_t)NROWS * DDIM + NROWS + 0] = m;
            out[(size_t)NROWS * DDIM + NROWS + 1] = m;
        }
    }
}

extern "C" void kernel_launch(void* const* d_in, const int* in_sizes, int n_in,
                              void* d_out, int out_size, void* d_ws, size_t ws_size,
                              hipStream_t stream)
{
    const float* z  = (const float*)d_in[0];
    const float* cb = (const float*)d_in[1];
    float* out = (float*)d_out;

    // bf16 pre-tiled codebook lives in d_out's z_st region (4 MB of 16.8 MB),
    // consumed by k_screen and fully overwritten afterwards by k_gather.
    unsigned short* cb_t = (unsigned short*)d_out;        // 4 MB

    char* ws = (char*)d_ws;
    unsigned long long* best = (unsigned long long*)ws;   // 131072 B
    float* e2      = (float*)(ws + 131072);               // 32768 B
    float* z2      = (float*)(ws + 163840);               // 65536 B
    float* accum   = (float*)(ws + 229376);
    unsigned* gctr = (unsigned*)(ws + 229380);
    unsigned* counters = (unsigned*)(ws + 229440);        // 16 shard counters, 64B apart
    unsigned* list = (unsigned*)(ws + 230464);
    unsigned C16 = 0;
    if (ws_size > 230464 + 64) {
        size_t c = (ws_size - 230464) / 4 / 16;
        if (c > (1u << 19)) c = (1u << 19);
        C16 = (unsigned)c;
    }

    k_convert<<<128, 256, 0, stream>>>(cb, cb_t, e2, best, accum, counters, gctr);
    k_screen<<<256, 1024, 0, stream>>>(z, cb, cb_t, z2, e2, best, counters, list, C16);
    k_rescore<<<1024, 256, 0, stream>>>(z, cb, z2, e2, list, counters, C16, best);
    k_gather<<<GATHER_BLOCKS, 1024, 0, stream>>>(z, cb, best, out, accum, gctr);
}

// Round 23
// 210.036 us; speedup vs baseline: 1.0675x; 1.0015x over previous
//
#include <hip/hip_runtime.h>

#define NROWS 16384
#define KCODES 8192
#define DDIM 256
#define MARGIN 1.0f
#define SEG 192
#define NCT 16     // 512-col tiles (block sweeps all 8192 cols)
#define GATHER_BLOCKS (NROWS / 16)

typedef __attribute__((ext_vector_type(8))) short short8;
typedef __attribute__((ext_vector_type(4))) float f32x4;

// ---------------- helpers ----------------
__device__ inline unsigned short f2bf(float x) {
    unsigned u = __float_as_uint(x);
    return (unsigned short)((u + 0x7FFFu + ((u >> 16) & 1u)) >> 16);  // RNE
}

__device__ inline unsigned mbcnt64(unsigned long long m) {
    unsigned lo = __builtin_amdgcn_mbcnt_lo((unsigned)m, 0u);
    return __builtin_amdgcn_mbcnt_hi((unsigned)(m >> 32), lo);
}

__device__ inline void exact_rescore(const float* __restrict__ z, const float* __restrict__ cb,
                                     const float* __restrict__ z2g, const float* __restrict__ e2g,
                                     int grow, int gcol, unsigned long long* best) {
    const float4* av = reinterpret_cast<const float4*>(z + (size_t)grow * DDIM);
    const float4* bv = reinterpret_cast<const float4*>(cb + (size_t)gcol * DDIM);
    float dot = 0.f;
    #pragma unroll 8
    for (int j = 0; j < 64; ++j) {
        const float4 xa = av[j], xb = bv[j];
        dot = fmaf(xa.x, xb.x, fmaf(xa.y, xb.y, fmaf(xa.z, xb.z, fmaf(xa.w, xb.w, dot))));
    }
    const float de = z2g[grow] + e2g[gcol] - 2.0f * dot;
    const unsigned long long key =
        ((unsigned long long)__float_as_uint(de) << 32) | (unsigned)gcol;
    atomicMin(best + grow, key);
}

// ---------------- convert cb fp32 -> bf16 pre-tiled fragment layout + e2 + init ----------------
// chunk (g, kb2): 1 KB, slot s: row g*16 + (s&15), k = kb2*32 + (s>>4)*8 .. +8
__global__ __launch_bounds__(256) void k_convert(
    const float* __restrict__ cb, unsigned short* __restrict__ cb_t,
    float* __restrict__ e2,
    unsigned long long* best, float* accum, unsigned* counters, unsigned* gctr)
{
    const int tid = threadIdx.x;
    const int bx = blockIdx.x;
    if (bx < 64) {
        const int gid = bx * 256 + tid;
        best[gid] = 0xFFFFFFFFFFFFFFFFull;
    }
    if (bx == 0) {
        if (tid < 16) counters[tid * 16] = 0u;
        if (tid == 0) { accum[0] = 0.0f; gctr[0] = 0u; }
    }
    const int g = bx * 4 + (tid >> 6);       // 512 groups over 128 blocks
    const int lane = tid & 63;
    const int row = g * 16 + (lane & 15);
    const int ko = (lane >> 4) * 8;
    float ss = 0.f;
    #pragma unroll
    for (int kb2 = 0; kb2 < 8; ++kb2) {
        const float4* src = reinterpret_cast<const float4*>(cb + (size_t)row * DDIM + kb2 * 32 + ko);
        const float4 a = src[0], b = src[1];
        ss += a.x * a.x + a.y * a.y + a.z * a.z + a.w * a.w
            + b.x * b.x + b.y * b.y + b.z * b.z + b.w * b.w;
        short8 p;
        p[0] = (short)f2bf(a.x); p[1] = (short)f2bf(a.y); p[2] = (short)f2bf(a.z); p[3] = (short)f2bf(a.w);
        p[4] = (short)f2bf(b.x); p[5] = (short)f2bf(b.y); p[6] = (short)f2bf(b.z); p[7] = (short)f2bf(b.w);
        *reinterpret_cast<short8*>(cb_t + (((size_t)(g * 8 + kb2)) << 9) + lane * 8) = p;
    }
    ss += __shfl_xor(ss, 16);
    ss += __shfl_xor(ss, 32);
    if (lane < 16) e2[g * 16 + lane] = ss;
}

// ---------------- MFMA screen: A in LDS, B straight from L2/L3 to registers ----------------
// 64 rows x ALL 8192 cols per block; wave tile 32x64 (acc[2][4]).
// K-loop is BARRIER-FREE: per step each wave loads its 4 B fragments from cb_t
// (wave-uniform base + lane*16, 1KB coalesced, L2/L3-resident) + 2 A ds_reads + 8 MFMA.
// Epilogue per tile: 2 lgkm-only barriers -> block-tight running threshold -> ballot emit.
// LDS: A 32K @0 | rowmin[8][64] @32768 | thrbuf[64] @34816 | wl 16xSEG @35072
__global__ __launch_bounds__(1024, 4) void k_screen(
    const float* __restrict__ z, const float* __restrict__ cbp,
    const unsigned short* __restrict__ cb_t,
    float* z2g, const float* __restrict__ e2g,
    unsigned long long* __restrict__ best,
    unsigned* __restrict__ counters, unsigned* __restrict__ list, unsigned C16)
{
    __shared__ __align__(16) char smem[47360];
    char* ldsA = smem;
    float* rowmin = (float*)(smem + 32768);    // [8][64]
    float* thrbuf = (float*)(smem + 34816);    // [64] running block min (incl. current tile)
    unsigned* wl_all = (unsigned*)(smem + 35072);

    const int tid = threadIdx.x;
    const int lane = tid & 63;
    const int wave = tid >> 6;     // 0..15
    const int wm = wave & 1;       // 32-row half
    const int wn = wave >> 1;      // 0..7 col-64 group
    const int lhi = lane >> 4;
    const int llo = lane & 15;

    const int rt = blockIdx.x;     // 256 blocks, 64-row bands
    const int row0 = rt * 64;

    // ---- prologue ----
    // fused z-convert: fp32 band -> bf16 fragments straight into ldsA (2 slots/thread)
    {
        const int c = tid >> 5;                // chunk 0..31: gl = c>>3, kb2 = c&7
        const int gl = c >> 3, kb2 = c & 7;
        const int sp = (tid & 31) * 2;
        #pragma unroll
        for (int i = 0; i < 2; ++i) {
            const int s = sp + i;
            const int row = gl * 16 + (s & 15);
            const int k = kb2 * 32 + (s >> 4) * 8;
            const float4* src = reinterpret_cast<const float4*>(z + (size_t)(row0 + row) * DDIM + k);
            const float4 a = src[0], b = src[1];
            short8 p;
            p[0] = (short)f2bf(a.x); p[1] = (short)f2bf(a.y); p[2] = (short)f2bf(a.z); p[3] = (short)f2bf(a.w);
            p[4] = (short)f2bf(b.x); p[5] = (short)f2bf(b.y); p[6] = (short)f2bf(b.z); p[7] = (short)f2bf(b.w);
            *reinterpret_cast<short8*>(ldsA + c * 1024 + s * 16) = p;
        }
    }

    // z2 for own band (additive per-row constant used by rescore keys)
    #pragma unroll
    for (int rr = 0; rr < 4; ++rr) {
        const int row = wave * 4 + rr;
        const float4 v = *reinterpret_cast<const float4*>(z + (size_t)(row0 + row) * DDIM + lane * 4);
        float s = v.x * v.x + v.y * v.y + v.z * v.z + v.w * v.w;
        #pragma unroll
        for (int off = 1; off < 64; off <<= 1) s += __shfl_xor(s, off);
        if (lane == 0) z2g[row0 + row] = s;
    }

    if (tid < 64) thrbuf[tid] = 3.0e38f;
    __syncthreads();   // ldsA writes + z2 complete

    unsigned* wl = wl_all + wave * SEG;

    #pragma unroll 1
    for (int ci = 0; ci < NCT; ++ci) {
        f32x4 acc[2][4];
        #pragma unroll
        for (int i = 0; i < 2; ++i)
            #pragma unroll
            for (int j = 0; j < 4; ++j) { acc[i][j][0]=0.f; acc[i][j][1]=0.f; acc[i][j][2]=0.f; acc[i][j][3]=0.f; }

        // ---- K loop: 8 steps of K=32, barrier-free, B from global (L2/L3) ----
        const char* bbase = (const char*)cb_t + (((size_t)((ci * 32 + wn * 4)) * 8) << 10) + lane * 16;
        #pragma unroll
        for (int kb2 = 0; kb2 < 8; ++kb2) {
            short8 bfr[4];
            #pragma unroll
            for (int fn = 0; fn < 4; ++fn)
                bfr[fn] = *reinterpret_cast<const short8*>(bbase + fn * 8192 + kb2 * 1024);
            #pragma unroll
            for (int fm = 0; fm < 2; ++fm) {
                const short8 af = *reinterpret_cast<const short8*>(
                    ldsA + (((wm * 2 + fm) * 8) + kb2) * 1024 + lane * 16);
                #pragma unroll
                for (int fn = 0; fn < 4; ++fn)
                    acc[fm][fn] = __builtin_amdgcn_mfma_f32_16x16x32_bf16(af, bfr[fn], acc[fm][fn], 0, 0, 0);
            }
        }

        // ---- epilogue: block-tight threshold (2 lgkm-only barriers) ----
        const int c0 = ci * 512 + wn * 64 + llo;
        float e2c[4];
        #pragma unroll
        for (int fn = 0; fn < 4; ++fn) e2c[fn] = e2g[c0 + fn * 16];

        // phase A: per-wave per-row min over this tile's 64-col slice
        #pragma unroll
        for (int fm = 0; fm < 2; ++fm) {
            #pragma unroll
            for (int rg = 0; rg < 4; ++rg) {
                const int rl = wm * 32 + fm * 16 + lhi * 4 + rg;
                float d[4];
                #pragma unroll
                for (int fn = 0; fn < 4; ++fn) d[fn] = fmaf(-2.0f, acc[fm][fn][rg], e2c[fn]);
                float m = fminf(fminf(d[0], d[1]), fminf(d[2], d[3]));
                #pragma unroll
                for (int off = 1; off < 16; off <<= 1) m = fminf(m, __shfl_xor(m, off));
                if (llo == 0) rowmin[wn * 64 + rl] = m;
            }
        }
        asm volatile("s_waitcnt lgkmcnt(0)" ::: "memory");
        __builtin_amdgcn_s_barrier();
        __builtin_amdgcn_sched_barrier(0);

        // merge: running block min now INCLUDES the current tile
        if (tid < 64) {
            float a = rowmin[tid];
            #pragma unroll
            for (int q = 1; q < 8; ++q) a = fminf(a, rowmin[q * 64 + tid]);
            thrbuf[tid] = fminf(thrbuf[tid], a);
        }
        asm volatile("s_waitcnt lgkmcnt(0)" ::: "memory");
        __builtin_amdgcn_s_barrier();
        __builtin_amdgcn_sched_barrier(0);

        // phase B: emit vs tight threshold (recompute d from acc)
        unsigned wcount = 0;
        #pragma unroll
        for (int fm = 0; fm < 2; ++fm) {
            #pragma unroll
            for (int rg = 0; rg < 4; ++rg) {
                const int rl = wm * 32 + fm * 16 + lhi * 4 + rg;
                const float thr = thrbuf[rl] + MARGIN;
                float d[4];
                #pragma unroll
                for (int fn = 0; fn < 4; ++fn) d[fn] = fmaf(-2.0f, acc[fm][fn][rg], e2c[fn]);
                const bool hit = (d[0] <= thr) | (d[1] <= thr) | (d[2] <= thr) | (d[3] <= thr);
                if (__any(hit)) {
                    const int grow = row0 + rl;
                    #pragma unroll
                    for (int fn = 0; fn < 4; ++fn) {
                        const bool p = d[fn] <= thr;
                        const unsigned long long mask = __ballot(p);
                        if (mask) {
                            if (p) {
                                const unsigned pos = wcount + mbcnt64(mask);
                                const unsigned v = ((unsigned)grow << 13) | (unsigned)(c0 + fn * 16);
                                if (pos < SEG) wl[pos] = v;
                                else exact_rescore(z, cbp, z2g, e2g, grow, c0 + fn * 16, best);
                            }
                            wcount += (unsigned)__popcll(mask);
                        }
                    }
                }
            }
        }

        // per-tile flush: one atomic per wave to its shard
        const unsigned n = wcount < SEG ? wcount : SEG;
        unsigned base = 0;
        if (lane == 0 && n) base = atomicAdd(&counters[wave * 16], n);
        base = (unsigned)__shfl((int)base, 0);
        for (unsigned i = lane; i < n; i += 64) {
            const unsigned v = wl[i];
            const unsigned slot = base + i;
            if (slot < C16) list[(size_t)wave * C16 + slot] = v;
            else exact_rescore(z, cbp, z2g, e2g, (int)(v >> 13), (int)(v & 8191u), best);
        }
    }
}

// ---------------- exact rescore of sharded candidate lists (wave per candidate) ----------------
__global__ __launch_bounds__(256) void k_rescore(
    const float* __restrict__ z, const float* __restrict__ cbp,
    const float* __restrict__ z2g, const float* __restrict__ e2g,
    const unsigned* __restrict__ list, const unsigned* __restrict__ counters, unsigned C16,
    unsigned long long* best)
{
    const unsigned wid = (blockIdx.x * blockDim.x + threadIdx.x) >> 6;
    const unsigned nw = (gridDim.x * blockDim.x) >> 6;
    const int lane = threadIdx.x & 63;
    #pragma unroll 1
    for (int s = 0; s < 16; ++s) {
        const unsigned n = min(counters[s * 16], C16);
        const unsigned* shard = list + (size_t)s * C16;
        for (unsigned i = wid; i < n; i += nw) {
            const unsigned v = shard[i];
            const unsigned row = v >> 13, col = v & 8191u;
            const float4 a = *reinterpret_cast<const float4*>(z + (size_t)row * DDIM + lane * 4);
            const float4 b = *reinterpret_cast<const float4*>(cbp + (size_t)col * DDIM + lane * 4);
            float sdot = fmaf(a.x, b.x, fmaf(a.y, b.y, fmaf(a.z, b.z, a.w * b.w)));
            #pragma unroll
            for (int off = 1; off < 64; off <<= 1) sdot += __shfl_xor(sdot, off);
            if (lane == 0) {
                const float de = z2g[row] + e2g[col] - 2.0f * sdot;
                const unsigned long long key =
                    ((unsigned long long)__float_as_uint(de) << 32) | col;
                atomicMin(&best[row], key);
            }
        }
    }
}

// ---------------- gather + z_st + loss + final scalars (ticket) ----------------
__global__ __launch_bounds__(1024) void k_gather(
    const float* __restrict__ z, const float* __restrict__ cbp,
    const unsigned long long* __restrict__ best,
    float* __restrict__ out, float* __restrict__ accum, unsigned* __restrict__ gctr)
{
    __shared__ float wsum[16];
    const int tid = threadIdx.x;
    const int row = blockIdx.x * 16 + (tid >> 6);
    const int lane = tid & 63;
    const unsigned k = (unsigned)(best[row] & 0xFFFFFFFFull);
    const float4 ze = *reinterpret_cast<const float4*>(z + (size_t)row * DDIM + lane * 4);
    const float4 cq = *reinterpret_cast<const float4*>(cbp + (size_t)k * DDIM + lane * 4);
    float4 zst;
    zst.x = ze.x + (cq.x - ze.x); zst.y = ze.y + (cq.y - ze.y);
    zst.z = ze.z + (cq.z - ze.z); zst.w = ze.w + (cq.w - ze.w);
    *reinterpret_cast<float4*>(out + (size_t)row * DDIM + lane * 4) = zst;
    const float dx = cq.x - ze.x, dy = cq.y - ze.y, dz = cq.z - ze.z, dw = cq.w - ze.w;
    float s = dx * dx + dy * dy + dz * dz + dw * dw;
    #pragma unroll
    for (int off = 32; off > 0; off >>= 1) s += __shfl_down(s, off);
    if (lane == 0) {
        wsum[tid >> 6] = s;
        out[(size_t)NROWS * DDIM + row] = (float)k;
    }
    __syncthreads();
    if (tid == 0) {
        float tot = 0.f;
        #pragma unroll
        for (int i = 0; i < 16; ++i) tot += wsum[i];
        atomicAdd(accum, tot);
        __threadfence();
        const unsigned t = atomicAdd(gctr, 1u);
        if (t == GATHER_BLOCKS - 1) {
            const float total = atomicAdd(accum, 0.0f);
            const float m = total / (float)(NROWS * DDIM);
            out[(size_t)NROWS * DDIM + NROWS + 0] = m;
            out[(size_t)NROWS * DDIM + NROWS + 1] = m;
        }
    }
}

extern "C" void kernel_launch(void* const* d_in, const int* in_sizes, int n_in,
                              void* d_out, int out_size, void* d_ws, size_t ws_size,
                              hipStream_t stream)
{
    const float* z  = (const float*)d_in[0];
    const float* cb = (const float*)d_in[1];
    float* out = (float*)d_out;

    // bf16 pre-tiled codebook lives in d_out's z_st region (4 MB of 16.8 MB),
    // consumed by k_screen and fully overwritten afterwards by k_gather.
    unsigned short* cb_t = (unsigned short*)d_out;        // 4 MB

    char* ws = (char*)d_ws;
    unsigned long long* best = (unsigned long long*)ws;   // 131072 B
    float* e2      = (float*)(ws + 131072);               // 32768 B
    float* z2      = (float*)(ws + 163840);               // 65536 B
    float* accum   = (float*)(ws + 229376);
    unsigned* gctr = (unsigned*)(ws + 229380);
    unsigned* counters = (unsigned*)(ws + 229440);        // 16 shard counters, 64B apart
    unsigned* list = (unsigned*)(ws + 230464);
    unsigned C16 = 0;
    if (ws_size > 230464 + 64) {
        size_t c = (ws_size - 230464) / 4 / 16;
        if (c > (1u << 19)) c = (1u << 19);
        C16 = (unsigned)c;
    }

    k_convert<<<128, 256, 0, stream>>>(cb, cb_t, e2, best, accum, counters, gctr);
    k_screen<<<256, 1024, 0, stream>>>(z, cb, cb_t, z2, e2, best, counters, list, C16);
    k_rescore<<<1024, 256, 0, stream>>>(z, cb, z2, e2, list, counters, C16, best);
    k_gather<<<GATHER_BLOCKS, 1024, 0, stream>>>(z, cb, best, out, accum, gctr);
}

// Round 24
// 201.872 us; speedup vs baseline: 1.1107x; 1.0404x over previous
//
#include <hip/hip_runtime.h>

#define NROWS 16384
#define KCODES 8192
#define DDIM 256
#define MARGIN 0.75f
#define SEG 192
#define NCT 16     // 512-col tiles (block sweeps all 8192 cols)
#define GATHER_BLOCKS (NROWS / 16)

typedef __attribute__((ext_vector_type(8))) short short8;
typedef __attribute__((ext_vector_type(4))) float f32x4;

// ---------------- helpers ----------------
__device__ inline unsigned short f2bf(float x) {
    unsigned u = __float_as_uint(x);
    return (unsigned short)((u + 0x7FFFu + ((u >> 16) & 1u)) >> 16);  // RNE
}

__device__ inline unsigned mbcnt64(unsigned long long m) {
    unsigned lo = __builtin_amdgcn_mbcnt_lo((unsigned)m, 0u);
    return __builtin_amdgcn_mbcnt_hi((unsigned)(m >> 32), lo);
}

__device__ inline void exact_rescore(const float* __restrict__ z, const float* __restrict__ cb,
                                     const float* __restrict__ z2g, const float* __restrict__ e2g,
                                     int grow, int gcol, unsigned long long* best) {
    const float4* av = reinterpret_cast<const float4*>(z + (size_t)grow * DDIM);
    const float4* bv = reinterpret_cast<const float4*>(cb + (size_t)gcol * DDIM);
    float dot = 0.f;
    #pragma unroll 8
    for (int j = 0; j < 64; ++j) {
        const float4 xa = av[j], xb = bv[j];
        dot = fmaf(xa.x, xb.x, fmaf(xa.y, xb.y, fmaf(xa.z, xb.z, fmaf(xa.w, xb.w, dot))));
    }
    const float de = z2g[grow] + e2g[gcol] - 2.0f * dot;
    const unsigned long long key =
        ((unsigned long long)__float_as_uint(de) << 32) | (unsigned)gcol;
    atomicMin(best + grow, key);
}

// ---------------- convert cb fp32 -> bf16 pre-tiled fragment layout + e2 + init ----------------
// chunk (g, kb2): 1 KB, slot s: row g*16 + (s&15), k = kb2*32 + (s>>4)*8 .. +8
// 256 blocks x 128 threads: 2 groups per block (1 block/CU).
__global__ __launch_bounds__(128) void k_convert(
    const float* __restrict__ cb, unsigned short* __restrict__ cb_t,
    float* __restrict__ e2,
    unsigned long long* best, float* accum, unsigned* counters, unsigned* gctr)
{
    const int tid = threadIdx.x;
    const int bx = blockIdx.x;
    if (bx < 128) {
        const int gid = bx * 128 + tid;
        best[gid] = 0xFFFFFFFFFFFFFFFFull;
    }
    if (bx == 0) {
        if (tid < 16) counters[tid * 16] = 0u;
        if (tid == 0) { accum[0] = 0.0f; gctr[0] = 0u; }
    }
    const int g = bx * 2 + (tid >> 6);       // 512 groups over 256 blocks
    const int lane = tid & 63;
    const int row = g * 16 + (lane & 15);
    const int ko = (lane >> 4) * 8;
    float ss = 0.f;
    #pragma unroll
    for (int kb2 = 0; kb2 < 8; ++kb2) {
        const float4* src = reinterpret_cast<const float4*>(cb + (size_t)row * DDIM + kb2 * 32 + ko);
        const float4 a = src[0], b = src[1];
        ss += a.x * a.x + a.y * a.y + a.z * a.z + a.w * a.w
            + b.x * b.x + b.y * b.y + b.z * b.z + b.w * b.w;
        short8 p;
        p[0] = (short)f2bf(a.x); p[1] = (short)f2bf(a.y); p[2] = (short)f2bf(a.z); p[3] = (short)f2bf(a.w);
        p[4] = (short)f2bf(b.x); p[5] = (short)f2bf(b.y); p[6] = (short)f2bf(b.z); p[7] = (short)f2bf(b.w);
        *reinterpret_cast<short8*>(cb_t + (((size_t)(g * 8 + kb2)) << 9) + lane * 8) = p;
    }
    ss += __shfl_xor(ss, 16);
    ss += __shfl_xor(ss, 32);
    if (lane < 16) e2[g * 16 + lane] = ss;
}

// ---------------- MFMA screen: A in LDS, B straight from L2/L3 to registers ----------------
// 64 rows x ALL 8192 cols per block; wave tile 32x64 (acc[2][4]).
// K-loop is BARRIER-FREE: per step each wave loads its 4 B fragments from cb_t
// (wave-uniform base + lane*16, 1KB coalesced, L2/L3-resident) + 2 A ds_reads + 8 MFMA.
// Epilogue per tile: 2 lgkm-only barriers -> block-tight running threshold -> ballot emit.
// LDS: A 32K @0 | rowmin[8][64] @32768 | thrbuf[64] @34816 | wl 16xSEG @35072
__global__ __launch_bounds__(1024, 4) void k_screen(
    const float* __restrict__ z, const float* __restrict__ cbp,
    const unsigned short* __restrict__ cb_t,
    float* z2g, const float* __restrict__ e2g,
    unsigned long long* __restrict__ best,
    unsigned* __restrict__ counters, unsigned* __restrict__ list, unsigned C16)
{
    __shared__ __align__(16) char smem[47360];
    char* ldsA = smem;
    float* rowmin = (float*)(smem + 32768);    // [8][64]
    float* thrbuf = (float*)(smem + 34816);    // [64] running block min (incl. current tile)
    unsigned* wl_all = (unsigned*)(smem + 35072);

    const int tid = threadIdx.x;
    const int lane = tid & 63;
    const int wave = tid >> 6;     // 0..15
    const int wm = wave & 1;       // 32-row half
    const int wn = wave >> 1;      // 0..7 col-64 group
    const int lhi = lane >> 4;
    const int llo = lane & 15;

    const int rt = blockIdx.x;     // 256 blocks, 64-row bands
    const int row0 = rt * 64;

    // ---- prologue ----
    // fused z-convert: fp32 band -> bf16 fragments straight into ldsA (2 slots/thread)
    {
        const int c = tid >> 5;                // chunk 0..31: gl = c>>3, kb2 = c&7
        const int gl = c >> 3, kb2 = c & 7;
        const int sp = (tid & 31) * 2;
        #pragma unroll
        for (int i = 0; i < 2; ++i) {
            const int s = sp + i;
            const int row = gl * 16 + (s & 15);
            const int k = kb2 * 32 + (s >> 4) * 8;
            const float4* src = reinterpret_cast<const float4*>(z + (size_t)(row0 + row) * DDIM + k);
            const float4 a = src[0], b = src[1];
            short8 p;
            p[0] = (short)f2bf(a.x); p[1] = (short)f2bf(a.y); p[2] = (short)f2bf(a.z); p[3] = (short)f2bf(a.w);
            p[4] = (short)f2bf(b.x); p[5] = (short)f2bf(b.y); p[6] = (short)f2bf(b.z); p[7] = (short)f2bf(b.w);
            *reinterpret_cast<short8*>(ldsA + c * 1024 + s * 16) = p;
        }
    }

    // z2 for own band (additive per-row constant used by rescore keys)
    #pragma unroll
    for (int rr = 0; rr < 4; ++rr) {
        const int row = wave * 4 + rr;
        const float4 v = *reinterpret_cast<const float4*>(z + (size_t)(row0 + row) * DDIM + lane * 4);
        float s = v.x * v.x + v.y * v.y + v.z * v.z + v.w * v.w;
        #pragma unroll
        for (int off = 1; off < 64; off <<= 1) s += __shfl_xor(s, off);
        if (lane == 0) z2g[row0 + row] = s;
    }

    if (tid < 64) thrbuf[tid] = 3.0e38f;
    __syncthreads();   // ldsA writes + z2 complete

    unsigned* wl = wl_all + wave * SEG;

    #pragma unroll 1
    for (int ci = 0; ci < NCT; ++ci) {
        f32x4 acc[2][4];
        #pragma unroll
        for (int i = 0; i < 2; ++i)
            #pragma unroll
            for (int j = 0; j < 4; ++j) { acc[i][j][0]=0.f; acc[i][j][1]=0.f; acc[i][j][2]=0.f; acc[i][j][3]=0.f; }

        // ---- K loop: 8 steps of K=32, barrier-free, B from global (L2/L3) ----
        const char* bbase = (const char*)cb_t + (((size_t)((ci * 32 + wn * 4)) * 8) << 10) + lane * 16;
        #pragma unroll
        for (int kb2 = 0; kb2 < 8; ++kb2) {
            short8 bfr[4];
            #pragma unroll
            for (int fn = 0; fn < 4; ++fn)
                bfr[fn] = *reinterpret_cast<const short8*>(bbase + fn * 8192 + kb2 * 1024);
            #pragma unroll
            for (int fm = 0; fm < 2; ++fm) {
                const short8 af = *reinterpret_cast<const short8*>(
                    ldsA + (((wm * 2 + fm) * 8) + kb2) * 1024 + lane * 16);
                #pragma unroll
                for (int fn = 0; fn < 4; ++fn)
                    acc[fm][fn] = __builtin_amdgcn_mfma_f32_16x16x32_bf16(af, bfr[fn], acc[fm][fn], 0, 0, 0);
            }
        }

        // ---- epilogue: block-tight threshold (2 lgkm-only barriers) ----
        const int c0 = ci * 512 + wn * 64 + llo;
        float e2c[4];
        #pragma unroll
        for (int fn = 0; fn < 4; ++fn) e2c[fn] = e2g[c0 + fn * 16];

        // phase A: per-wave per-row min over this tile's 64-col slice
        #pragma unroll
        for (int fm = 0; fm < 2; ++fm) {
            #pragma unroll
            for (int rg = 0; rg < 4; ++rg) {
                const int rl = wm * 32 + fm * 16 + lhi * 4 + rg;
                float d[4];
                #pragma unroll
                for (int fn = 0; fn < 4; ++fn) d[fn] = fmaf(-2.0f, acc[fm][fn][rg], e2c[fn]);
                float m = fminf(fminf(d[0], d[1]), fminf(d[2], d[3]));
                #pragma unroll
                for (int off = 1; off < 16; off <<= 1) m = fminf(m, __shfl_xor(m, off));
                if (llo == 0) rowmin[wn * 64 + rl] = m;
            }
        }
        asm volatile("s_waitcnt lgkmcnt(0)" ::: "memory");
        __builtin_amdgcn_s_barrier();
        __builtin_amdgcn_sched_barrier(0);

        // merge: running block min now INCLUDES the current tile
        if (tid < 64) {
            float a = rowmin[tid];
            #pragma unroll
            for (int q = 1; q < 8; ++q) a = fminf(a, rowmin[q * 64 + tid]);
            thrbuf[tid] = fminf(thrbuf[tid], a);
        }
        asm volatile("s_waitcnt lgkmcnt(0)" ::: "memory");
        __builtin_amdgcn_s_barrier();
        __builtin_amdgcn_sched_barrier(0);

        // phase B: emit vs tight threshold (recompute d from acc)
        unsigned wcount = 0;
        #pragma unroll
        for (int fm = 0; fm < 2; ++fm) {
            #pragma unroll
            for (int rg = 0; rg < 4; ++rg) {
                const int rl = wm * 32 + fm * 16 + lhi * 4 + rg;
                const float thr = thrbuf[rl] + MARGIN;
                float d[4];
                #pragma unroll
                for (int fn = 0; fn < 4; ++fn) d[fn] = fmaf(-2.0f, acc[fm][fn][rg], e2c[fn]);
                const bool hit = (d[0] <= thr) | (d[1] <= thr) | (d[2] <= thr) | (d[3] <= thr);
                if (__any(hit)) {
                    const int grow = row0 + rl;
                    #pragma unroll
                    for (int fn = 0; fn < 4; ++fn) {
                        const bool p = d[fn] <= thr;
                        const unsigned long long mask = __ballot(p);
                        if (mask) {
                            if (p) {
                                const unsigned pos = wcount + mbcnt64(mask);
                                const unsigned v = ((unsigned)grow << 13) | (unsigned)(c0 + fn * 16);
                                if (pos < SEG) wl[pos] = v;
                                else exact_rescore(z, cbp, z2g, e2g, grow, c0 + fn * 16, best);
                            }
                            wcount += (unsigned)__popcll(mask);
                        }
                    }
                }
            }
        }

        // per-tile flush: one atomic per wave to its shard
        const unsigned n = wcount < SEG ? wcount : SEG;
        unsigned base = 0;
        if (lane == 0 && n) base = atomicAdd(&counters[wave * 16], n);
        base = (unsigned)__shfl((int)base, 0);
        for (unsigned i = lane; i < n; i += 64) {
            const unsigned v = wl[i];
            const unsigned slot = base + i;
            if (slot < C16) list[(size_t)wave * C16 + slot] = v;
            else exact_rescore(z, cbp, z2g, e2g, (int)(v >> 13), (int)(v & 8191u), best);
        }
    }
}

// ---------------- exact rescore of sharded candidate lists (wave per candidate) ----------------
__global__ __launch_bounds__(256) void k_rescore(
    const float* __restrict__ z, const float* __restrict__ cbp,
    const float* __restrict__ z2g, const float* __restrict__ e2g,
    const unsigned* __restrict__ list, const unsigned* __restrict__ counters, unsigned C16,
    unsigned long long* best)
{
    const unsigned wid = (blockIdx.x * blockDim.x + threadIdx.x) >> 6;
    const unsigned nw = (gridDim.x * blockDim.x) >> 6;
    const int lane = threadIdx.x & 63;
    #pragma unroll 1
    for (int s = 0; s < 16; ++s) {
        const unsigned n = min(counters[s * 16], C16);
        const unsigned* shard = list + (size_t)s * C16;
        for (unsigned i = wid; i < n; i += nw) {
            const unsigned v = shard[i];
            const unsigned row = v >> 13, col = v & 8191u;
            const float4 a = *reinterpret_cast<const float4*>(z + (size_t)row * DDIM + lane * 4);
            const float4 b = *reinterpret_cast<const float4*>(cbp + (size_t)col * DDIM + lane * 4);
            float sdot = fmaf(a.x, b.x, fmaf(a.y, b.y, fmaf(a.z, b.z, a.w * b.w)));
            #pragma unroll
            for (int off = 1; off < 64; off <<= 1) sdot += __shfl_xor(sdot, off);
            if (lane == 0) {
                const float de = z2g[row] + e2g[col] - 2.0f * sdot;
                const unsigned long long key =
                    ((unsigned long long)__float_as_uint(de) << 32) | col;
                atomicMin(&best[row], key);
            }
        }
    }
}

// ---------------- gather + z_st + loss + final scalars (ticket) ----------------
__global__ __launch_bounds__(1024) void k_gather(
    const float* __restrict__ z, const float* __restrict__ cbp,
    const unsigned long long* __restrict__ best,
    float* __restrict__ out, float* __restrict__ accum, unsigned* __restrict__ gctr)
{
    __shared__ float wsum[16];
    const int tid = threadIdx.x;
    const int row = blockIdx.x * 16 + (tid >> 6);
    const int lane = tid & 63;
    const unsigned k = (unsigned)(best[row] & 0xFFFFFFFFull);
    const float4 ze = *reinterpret_cast<const float4*>(z + (size_t)row * DDIM + lane * 4);
    const float4 cq = *reinterpret_cast<const float4*>(cbp + (size_t)k * DDIM + lane * 4);
    float4 zst;
    zst.x = ze.x + (cq.x - ze.x); zst.y = ze.y + (cq.y - ze.y);
    zst.z = ze.z + (cq.z - ze.z); zst.w = ze.w + (cq.w - ze.w);
    *reinterpret_cast<float4*>(out + (size_t)row * DDIM + lane * 4) = zst;
    const float dx = cq.x - ze.x, dy = cq.y - ze.y, dz = cq.z - ze.z, dw = cq.w - ze.w;
    float s = dx * dx + dy * dy + dz * dz + dw * dw;
    #pragma unroll
    for (int off = 32; off > 0; off >>= 1) s += __shfl_down(s, off);
    if (lane == 0) {
        wsum[tid >> 6] = s;
        out[(size_t)NROWS * DDIM + row] = (float)k;
    }
    __syncthreads();
    if (tid == 0) {
        float tot = 0.f;
        #pragma unroll
        for (int i = 0; i < 16; ++i) tot += wsum[i];
        atomicAdd(accum, tot);
        __threadfence();
        const unsigned t = atomicAdd(gctr, 1u);
        if (t == GATHER_BLOCKS - 1) {
            const float total = atomicAdd(accum, 0.0f);
            const float m = total / (float)(NROWS * DDIM);
            out[(size_t)NROWS * DDIM + NROWS + 0] = m;
            out[(size_t)NROWS * DDIM + NROWS + 1] = m;
        }
    }
}

extern "C" void kernel_launch(void* const* d_in, const int* in_sizes, int n_in,
                              void* d_out, int out_size, void* d_ws, size_t ws_size,
                              hipStream_t stream)
{
    const float* z  = (const float*)d_in[0];
    const float* cb = (const float*)d_in[1];
    float* out = (float*)d_out;

    // bf16 pre-tiled codebook lives in d_out's z_st region (4 MB of 16.8 MB),
    // consumed by k_screen and fully overwritten afterwards by k_gather.
    unsigned short* cb_t = (unsigned short*)d_out;        // 4 MB

    char* ws = (char*)d_ws;
    unsigned long long* best = (unsigned long long*)ws;   // 131072 B
    float* e2      = (float*)(ws + 131072);               // 32768 B
    float* z2      = (float*)(ws + 163840);               // 65536 B
    float* accum   = (float*)(ws + 229376);
    unsigned* gctr = (unsigned*)(ws + 229380);
    unsigned* counters = (unsigned*)(ws + 229440);        // 16 shard counters, 64B apart
    unsigned* list = (unsigned*)(ws + 230464);
    unsigned C16 = 0;
    if (ws_size > 230464 + 64) {
        size_t c = (ws_size - 230464) / 4 / 16;
        if (c > (1u << 19)) c = (1u << 19);
        C16 = (unsigned)c;
    }

    k_convert<<<256, 128, 0, stream>>>(cb, cb_t, e2, best, accum, counters, gctr);
    k_screen<<<256, 1024, 0, stream>>>(z, cb, cb_t, z2, e2, best, counters, list, C16);
    k_rescore<<<1024, 256, 0, stream>>>(z, cb, z2, e2, list, counters, C16, best);
    k_gather<<<GATHER_BLOCKS, 1024, 0, stream>>>(z, cb, best, out, accum, gctr);
}